// Round 1
// baseline (626.369 us; speedup 1.0000x reference)
//
#include <hip/hip_runtime.h>
#include <math.h>

#define K_DIM 4096
#define N_DIM 256
#define M_DIM 16384

typedef short bf8v __attribute__((ext_vector_type(8)));
typedef float f4v __attribute__((ext_vector_type(4)));

union FragU { unsigned u[4]; bf8v v; };

__device__ __forceinline__ void gl_lds16(const unsigned short* g, unsigned short* l) {
    __builtin_amdgcn_global_load_lds(
        (const __attribute__((address_space(1))) unsigned int*)g,
        (__attribute__((address_space(3))) unsigned int*)l, 16, 0, 0);
}

__device__ __forceinline__ unsigned short f2bf_rne(float f) {
    unsigned u = __float_as_uint(f);
    u += 0x7fffu + ((u >> 16) & 1u);
    return (unsigned short)(u >> 16);
}

// Split classical_weights (fp32, [K][N] row-major) into transposed bf16 hi/lo [N][K].
__global__ void split_w_kernel(const float* __restrict__ W,
                               unsigned short* __restrict__ Whi,
                               unsigned short* __restrict__ Wlo) {
    int n = blockIdx.x;
    for (int k = threadIdx.x; k < K_DIM; k += blockDim.x) {
        float f = W[(size_t)k * N_DIM + n];
        unsigned u = __float_as_uint(f);
        unsigned h = u + 0x7fffu + ((u >> 16) & 1u);     // RNE to bf16 (top 16)
        float r = f - __uint_as_float(h & 0xffff0000u);  // residual
        Whi[(size_t)n * K_DIM + k] = (unsigned short)(h >> 16);
        Wlo[(size_t)n * K_DIM + k] = (unsigned short)(__float_as_uint(r) >> 16);
    }
}

// beta[j] = bias[j] + (1/4096) * prod_{d,k} cos^2(uw[d, j, k])
// (state starts uniform along axis1 and _rotate preserves uniformity: row -> cos(a)*row)
__global__ void beta_kernel(const float* __restrict__ uw,
                            const float* __restrict__ bias,
                            float* __restrict__ beta) {
    int j = threadIdx.x;
    float p = 1.0f / 4096.0f;
    #pragma unroll
    for (int d = 0; d < 9; ++d) {
        const float* a = uw + (size_t)d * (K_DIM * N_DIM) + (size_t)j * N_DIM;
        #pragma unroll
        for (int k = 0; k < 3; ++k) {
            float c = cosf(a[k]);
            p *= c * c;
        }
    }
    beta[j] = bias[j] + p;
}

__device__ __forceinline__ void cvt8(float4 f0, float4 f1, FragU& hi, FragU& lo) {
    float f[8] = {f0.x, f0.y, f0.z, f0.w, f1.x, f1.y, f1.z, f1.w};
    #pragma unroll
    for (int i = 0; i < 4; ++i) {
        float x0 = f[2 * i], x1 = f[2 * i + 1];
        unsigned u0 = __float_as_uint(x0), u1 = __float_as_uint(x1);
        unsigned h0 = u0 + 0x7fffu + ((u0 >> 16) & 1u);
        unsigned h1 = u1 + 0x7fffu + ((u1 >> 16) & 1u);
        hi.u[i] = (h0 >> 16) | (h1 & 0xffff0000u);
        float r0 = x0 - __uint_as_float(h0 & 0xffff0000u);
        float r1 = x1 - __uint_as_float(h1 & 0xffff0000u);
        lo.u[i] = (__float_as_uint(r0) >> 16) | (__float_as_uint(r1) & 0xffff0000u);
    }
}

__device__ __forceinline__ f4v mfma_bf16(bf8v a, bf8v b, f4v c) {
    return __builtin_amdgcn_mfma_f32_16x16x32_bf16(a, b, c, 0, 0, 0);
}

// out[m, n] = tanh( sum_k x[m,k]*W[k,n] + beta[n] ), 3-term bf16 split GEMM.
// BM=64 BN=128 BK=32, 256 threads = 4 waves, wave-tile 32x64 (2x4 of 16x16x32).
__global__ __launch_bounds__(256, 2)
void gemm_tanh_kernel(const float* __restrict__ X,
                      const unsigned short* __restrict__ Whi,
                      const unsigned short* __restrict__ Wlo,
                      const float* __restrict__ beta,
                      float* __restrict__ out) {
    // B tiles in LDS, k-part-major layout: chunk c (16B) = [kpart=c>>7][row=c&127][8]
    __shared__ unsigned short sBh[128 * 32];
    __shared__ unsigned short sBl[128 * 32];

    const int t = threadIdx.x;
    const int n0 = blockIdx.x * 128;   // n-blocks adjacent in dispatch -> share x tile in L2
    const int m0 = blockIdx.y * 64;

    const int lane = t & 63;
    const int wave = t >> 6;
    const int wm = wave & 1;
    const int wn = wave >> 1;
    const int r16 = lane & 15;
    const int quad = lane >> 4;

    // B staging: thread t owns chunks t and 256+t.
    const int brow = t & 127;
    const int bk0 = (t >> 7) * 8;  // chunk t: kpart 0..1 ; chunk 256+t: kpart 2..3 -> +16
    const unsigned short* gbh0 = Whi + (size_t)(n0 + brow) * K_DIM + bk0;
    const unsigned short* gbl0 = Wlo + (size_t)(n0 + brow) * K_DIM + bk0;
    unsigned short* lbh0 = &sBh[(size_t)t * 8];
    unsigned short* lbh1 = &sBh[(size_t)(256 + t) * 8];
    unsigned short* lbl0 = &sBl[(size_t)t * 8];
    unsigned short* lbl1 = &sBl[(size_t)(256 + t) * 8];

    // A fragments straight from global (fp32), split in registers.
    const float* xr0 = X + (size_t)(m0 + wm * 32 + r16) * K_DIM + quad * 8;
    const float* xr1 = xr0 + (size_t)16 * K_DIM;

    f4v acc[2][4];
    #pragma unroll
    for (int mt = 0; mt < 2; ++mt)
        #pragma unroll
        for (int nt = 0; nt < 4; ++nt)
            acc[mt][nt] = (f4v)(0.0f);

    for (int kt = 0; kt < K_DIM; kt += 32) {
        // ---- stage B (async, direct to LDS) ----
        gl_lds16(gbh0 + kt, lbh0);
        gl_lds16(gbh0 + kt + 16, lbh1);
        gl_lds16(gbl0 + kt, lbl0);
        gl_lds16(gbl0 + kt + 16, lbl1);

        // ---- A loads + hi/lo split (registers, overlaps load_lds latency) ----
        float4 a00 = *(const float4*)(xr0 + kt);
        float4 a01 = *(const float4*)(xr0 + kt + 4);
        float4 a10 = *(const float4*)(xr1 + kt);
        float4 a11 = *(const float4*)(xr1 + kt + 4);
        FragU ah0, al0, ah1, al1;
        cvt8(a00, a01, ah0, al0);
        cvt8(a10, a11, ah1, al1);

        __syncthreads();  // sB ready (vmcnt(0) drained by barrier semantics)

        FragU bh[4], bl[4];
        #pragma unroll
        for (int nt = 0; nt < 4; ++nt) {
            int row = wn * 64 + nt * 16 + r16;
            bh[nt].v = *(const bf8v*)&sBh[(size_t)(quad * 128 + row) * 8];
            bl[nt].v = *(const bf8v*)&sBl[(size_t)(quad * 128 + row) * 8];
        }
        #pragma unroll
        for (int nt = 0; nt < 4; ++nt) {
            acc[0][nt] = mfma_bf16(ah0.v, bh[nt].v, acc[0][nt]);
            acc[0][nt] = mfma_bf16(al0.v, bh[nt].v, acc[0][nt]);
            acc[0][nt] = mfma_bf16(ah0.v, bl[nt].v, acc[0][nt]);
            acc[1][nt] = mfma_bf16(ah1.v, bh[nt].v, acc[1][nt]);
            acc[1][nt] = mfma_bf16(al1.v, bh[nt].v, acc[1][nt]);
            acc[1][nt] = mfma_bf16(ah1.v, bl[nt].v, acc[1][nt]);
        }
        __syncthreads();  // protect sB before next stage
    }

    // ---- epilogue: + beta, tanh, store ----
    const int nbase = n0 + wn * 64;
    float bet[4];
    #pragma unroll
    for (int nt = 0; nt < 4; ++nt) bet[nt] = beta[nbase + nt * 16 + r16];

    const int mbase = m0 + wm * 32;
    #pragma unroll
    for (int mt = 0; mt < 2; ++mt) {
        #pragma unroll
        for (int nt = 0; nt < 4; ++nt) {
            const int col = nbase + nt * 16 + r16;
            #pragma unroll
            for (int r = 0; r < 4; ++r) {
                const int row = mbase + mt * 16 + quad * 4 + r;
                out[(size_t)row * N_DIM + col] = tanhf(acc[mt][nt][r] + bet[nt]);
            }
        }
    }
}

extern "C" void kernel_launch(void* const* d_in, const int* in_sizes, int n_in,
                              void* d_out, int out_size, void* d_ws, size_t ws_size,
                              hipStream_t stream) {
    const float* x    = (const float*)d_in[0];
    const float* uw   = (const float*)d_in[1];
    const float* W    = (const float*)d_in[2];
    const float* bias = (const float*)d_in[3];
    float* out = (float*)d_out;

    // workspace layout: Whi (2 MB) | Wlo (2 MB) | beta (1 KB)
    char* ws = (char*)d_ws;
    unsigned short* whi = (unsigned short*)(ws);
    unsigned short* wlo = (unsigned short*)(ws + (size_t)2 * 1024 * 1024);
    float* beta = (float*)(ws + (size_t)4 * 1024 * 1024);

    split_w_kernel<<<N_DIM, 256, 0, stream>>>(W, whi, wlo);
    beta_kernel<<<1, 256, 0, stream>>>(uw, bias, beta);

    dim3 grid(N_DIM / 128, M_DIM / 64);  // n-major so paired n-blocks share x in L2
    gemm_tanh_kernel<<<grid, 256, 0, stream>>>(x, whi, wlo, beta, out);
}

// Round 2
// 611.125 us; speedup vs baseline: 1.0249x; 1.0249x over previous
//
#include <hip/hip_runtime.h>
#include <math.h>

#define K_DIM 4096
#define N_DIM 256
#define M_DIM 16384

typedef short bf8v __attribute__((ext_vector_type(8)));
typedef float f4v __attribute__((ext_vector_type(4)));
typedef unsigned short us8 __attribute__((ext_vector_type(8)));

union FragU { unsigned u[4]; bf8v v; };

__device__ __forceinline__ void gl_lds16(const unsigned short* g, unsigned short* l) {
    __builtin_amdgcn_global_load_lds(
        (const __attribute__((address_space(1))) unsigned int*)g,
        (__attribute__((address_space(3))) unsigned int*)l, 16, 0, 0);
}

// Split classical_weights (fp32, [K][N] row-major) into transposed bf16 hi/lo [N][K].
// Coalesced via 64x64 LDS tile transpose (old version read 1KB-stride columns).
__global__ void split_w_kernel(const float* __restrict__ W,
                               unsigned short* __restrict__ Whi,
                               unsigned short* __restrict__ Wlo) {
    __shared__ float tile[64][65];
    const int kb = blockIdx.x * 64;
    const int nb = blockIdx.y * 64;
    const int t = threadIdx.x;
    const int ln = t & 63, lk = t >> 6;
    #pragma unroll
    for (int i = 0; i < 16; ++i)
        tile[lk + 4 * i][ln] = W[(size_t)(kb + lk + 4 * i) * N_DIM + nb + ln];
    __syncthreads();
    const int n = t >> 2, k0 = (t & 3) * 16;
    unsigned short h[16], l[16];
    #pragma unroll
    for (int i = 0; i < 16; ++i) {
        float f = tile[k0 + i][n];
        unsigned u = __float_as_uint(f);
        unsigned hh = u + 0x7fffu + ((u >> 16) & 1u);       // RNE to bf16
        float r = f - __uint_as_float(hh & 0xffff0000u);    // residual
        h[i] = (unsigned short)(hh >> 16);
        l[i] = (unsigned short)(__float_as_uint(r) >> 16);
    }
    size_t o = (size_t)(nb + n) * K_DIM + kb + k0;
    *(us8*)&Whi[o] = *(us8*)&h[0];
    *(us8*)&Whi[o + 8] = *(us8*)&h[8];
    *(us8*)&Wlo[o] = *(us8*)&l[0];
    *(us8*)&Wlo[o + 8] = *(us8*)&l[8];
}

// beta[j] = bias[j] + (1/4096) * prod_{d,k} cos^2(uw[d, j, k])
// (state starts uniform along axis1 and _rotate preserves uniformity: row -> cos(a)*row)
__global__ void beta_kernel(const float* __restrict__ uw,
                            const float* __restrict__ bias,
                            float* __restrict__ beta) {
    int j = threadIdx.x;
    float p = 1.0f / 4096.0f;
    #pragma unroll
    for (int d = 0; d < 9; ++d) {
        const float* a = uw + (size_t)d * (K_DIM * N_DIM) + (size_t)j * N_DIM;
        #pragma unroll
        for (int k = 0; k < 3; ++k) {
            float c = cosf(a[k]);
            p *= c * c;
        }
    }
    beta[j] = bias[j] + p;
}

__device__ __forceinline__ void cvt8(float4 f0, float4 f1, FragU& hi, FragU& lo) {
    float f[8] = {f0.x, f0.y, f0.z, f0.w, f1.x, f1.y, f1.z, f1.w};
    #pragma unroll
    for (int i = 0; i < 4; ++i) {
        float x0 = f[2 * i], x1 = f[2 * i + 1];
        unsigned u0 = __float_as_uint(x0), u1 = __float_as_uint(x1);
        unsigned h0 = u0 + 0x7fffu + ((u0 >> 16) & 1u);
        unsigned h1 = u1 + 0x7fffu + ((u1 >> 16) & 1u);
        hi.u[i] = (h0 >> 16) | (h1 & 0xffff0000u);
        float r0 = x0 - __uint_as_float(h0 & 0xffff0000u);
        float r1 = x1 - __uint_as_float(h1 & 0xffff0000u);
        lo.u[i] = (__float_as_uint(r0) >> 16) | (__float_as_uint(r1) & 0xffff0000u);
    }
}

__device__ __forceinline__ f4v mfma_bf16(bf8v a, bf8v b, f4v c) {
    return __builtin_amdgcn_mfma_f32_16x16x32_bf16(a, b, c, 0, 0, 0);
}

// out[m, n] = tanh( sum_k x[m,k]*W[k,n] + beta[n] ), 3-term bf16 split GEMM.
// BM=64 BN=128 BK=64, 256 threads = 4 waves, wave-tile 32x64.
// Double-buffered LDS for B, ONE barrier per 64-deep K-stage; A prefetched
// into registers; stage s+1 VMEM issued before stage-s MFMAs so the
// vmcnt(0) drain at the barrier overlaps ~48 MFMA/wave of compute.
__global__ __launch_bounds__(256, 2)
void gemm_tanh_kernel(const float* __restrict__ X,
                      const unsigned short* __restrict__ Whi,
                      const unsigned short* __restrict__ Wlo,
                      const float* __restrict__ beta,
                      float* __restrict__ out) {
    // [buf][hi/lo][kpart*128 + nrow][8 shorts] -> 64 KB total, 2 blocks/CU
    __shared__ unsigned short sB[2][2][128 * 8 * 8];

    const int t = threadIdx.x;
    const int n0 = blockIdx.x * 128;   // x-fastest dispatch: paired n-blocks share x in L2
    const int m0 = blockIdx.y * 64;

    const int lane = t & 63;
    const int wave = t >> 6;
    const int wm = wave & 1;
    const int wn = wave >> 1;
    const int r16 = lane & 15;
    const int quad = lane >> 4;

    // ---- B staging: thread t stages rows (t&127), kparts (t>>7)*4 .. +3 ----
    const int brow = t & 127;
    const int kpb = (t >> 7) * 4;
    const unsigned short* gbh = Whi + (size_t)(n0 + brow) * K_DIM + kpb * 8;
    const unsigned short* gbl = Wlo + (size_t)(n0 + brow) * K_DIM + kpb * 8;
    unsigned short* lh[2][4];
    unsigned short* ll[2][4];
    #pragma unroll
    for (int b = 0; b < 2; ++b)
        #pragma unroll
        for (int j = 0; j < 4; ++j) {
            lh[b][j] = &sB[b][0][((kpb + j) * 128 + brow) * 8];
            ll[b][j] = &sB[b][1][((kpb + j) * 128 + brow) * 8];
        }

    // ---- A pointers (direct from global, fp32) ----
    const float* xr0 = X + (size_t)(m0 + wm * 32 + r16) * K_DIM + quad * 8;
    const float* xr1 = xr0 + (size_t)16 * K_DIM;

    f4v acc[2][4];
    #pragma unroll
    for (int mt = 0; mt < 2; ++mt)
        #pragma unroll
        for (int nt = 0; nt < 4; ++nt)
            acc[mt][nt] = (f4v)(0.0f);

    // ---- prologue: stage 0 ----
    #pragma unroll
    for (int j = 0; j < 4; ++j) {
        gl_lds16(gbh + j * 8, lh[0][j]);
        gl_lds16(gbl + j * 8, ll[0][j]);
    }
    float4 an[8];  // [row(2)][step(2)][half(2)]
    #pragma unroll
    for (int r = 0; r < 2; ++r)
        #pragma unroll
        for (int st = 0; st < 2; ++st)
            #pragma unroll
            for (int hf = 0; hf < 2; ++hf)
                an[r * 4 + st * 2 + hf] =
                    *(const float4*)((r ? xr1 : xr0) + st * 32 + hf * 4);
    __syncthreads();

    for (int s = 0; s < K_DIM / 64; ++s) {
        const int buf = s & 1;
        const int ktn = (s + 1) * 64;

        // ---- issue next-stage B (async -> other LDS buffer) ----
        if (s + 1 < K_DIM / 64) {
            #pragma unroll
            for (int j = 0; j < 4; ++j) {
                gl_lds16(gbh + ktn + j * 8, lh[buf ^ 1][j]);
                gl_lds16(gbl + ktn + j * 8, ll[buf ^ 1][j]);
            }
        }

        // ---- convert current A regs to bf16 hi/lo frags ----
        FragU ah[2][2], al[2][2];
        #pragma unroll
        for (int r = 0; r < 2; ++r)
            #pragma unroll
            for (int st = 0; st < 2; ++st)
                cvt8(an[r * 4 + st * 2], an[r * 4 + st * 2 + 1], ah[r][st], al[r][st]);

        // ---- issue next-stage A loads (regs free after cvt) ----
        if (s + 1 < K_DIM / 64) {
            #pragma unroll
            for (int r = 0; r < 2; ++r)
                #pragma unroll
                for (int st = 0; st < 2; ++st)
                    #pragma unroll
                    for (int hf = 0; hf < 2; ++hf)
                        an[r * 4 + st * 2 + hf] =
                            *(const float4*)((r ? xr1 : xr0) + ktn + st * 32 + hf * 4);
        }

        // ---- compute on current buffer: 2 k-steps x (2m x 4n) x 3 terms ----
        #pragma unroll
        for (int st = 0; st < 2; ++st) {
            FragU bh[4], bl[4];
            #pragma unroll
            for (int nt = 0; nt < 4; ++nt) {
                int row = wn * 64 + nt * 16 + r16;
                int kp = st * 4 + quad;
                bh[nt].v = *(const bf8v*)&sB[buf][0][(kp * 128 + row) * 8];
                bl[nt].v = *(const bf8v*)&sB[buf][1][(kp * 128 + row) * 8];
            }
            #pragma unroll
            for (int nt = 0; nt < 4; ++nt) {
                acc[0][nt] = mfma_bf16(ah[0][st].v, bh[nt].v, acc[0][nt]);
                acc[0][nt] = mfma_bf16(al[0][st].v, bh[nt].v, acc[0][nt]);
                acc[0][nt] = mfma_bf16(ah[0][st].v, bl[nt].v, acc[0][nt]);
                acc[1][nt] = mfma_bf16(ah[1][st].v, bh[nt].v, acc[1][nt]);
                acc[1][nt] = mfma_bf16(al[1][st].v, bh[nt].v, acc[1][nt]);
                acc[1][nt] = mfma_bf16(ah[1][st].v, bl[nt].v, acc[1][nt]);
            }
        }

        // One barrier: ensures next buffer staged (vmcnt drain) AND that all
        // waves finished reading buf before iter s+1's staging overwrites buf^1... 
        // (iter s+2 writes buf, so reads of buf must complete before s+1's barrier)
        __syncthreads();
    }

    // ---- epilogue: + beta, tanh, store ----
    const int nbase = n0 + wn * 64;
    float bet[4];
    #pragma unroll
    for (int nt = 0; nt < 4; ++nt) bet[nt] = beta[nbase + nt * 16 + r16];

    const int mbase = m0 + wm * 32;
    #pragma unroll
    for (int mt = 0; mt < 2; ++mt) {
        #pragma unroll
        for (int nt = 0; nt < 4; ++nt) {
            const int col = nbase + nt * 16 + r16;
            #pragma unroll
            for (int r = 0; r < 4; ++r) {
                const int row = mbase + mt * 16 + quad * 4 + r;
                out[(size_t)row * N_DIM + col] = tanhf(acc[mt][nt][r] + bet[nt]);
            }
        }
    }
}

extern "C" void kernel_launch(void* const* d_in, const int* in_sizes, int n_in,
                              void* d_out, int out_size, void* d_ws, size_t ws_size,
                              hipStream_t stream) {
    const float* x    = (const float*)d_in[0];
    const float* uw   = (const float*)d_in[1];
    const float* W    = (const float*)d_in[2];
    const float* bias = (const float*)d_in[3];
    float* out = (float*)d_out;

    // workspace layout: Whi (2 MB) | Wlo (2 MB) | beta (1 KB)
    char* ws = (char*)d_ws;
    unsigned short* whi = (unsigned short*)(ws);
    unsigned short* wlo = (unsigned short*)(ws + (size_t)2 * 1024 * 1024);
    float* beta = (float*)(ws + (size_t)4 * 1024 * 1024);

    split_w_kernel<<<dim3(K_DIM / 64, N_DIM / 64), 256, 0, stream>>>(W, whi, wlo);
    beta_kernel<<<1, 256, 0, stream>>>(uw, bias, beta);

    dim3 grid(N_DIM / 128, M_DIM / 64);
    gemm_tanh_kernel<<<grid, 256, 0, stream>>>(x, whi, wlo, beta, out);
}

// Round 3
// 499.977 us; speedup vs baseline: 1.2528x; 1.2223x over previous
//
#include <hip/hip_runtime.h>
#include <math.h>

#define K_DIM 4096
#define N_DIM 256
#define M_DIM 16384
#define BK 32
#define NSTAGES (K_DIM / BK)   // 128
#define BUF_BYTES 24576        // A 8K | Bh 8K | Bl 8K

typedef short bf8v __attribute__((ext_vector_type(8)));
typedef float f4v __attribute__((ext_vector_type(4)));
typedef unsigned short us8 __attribute__((ext_vector_type(8)));

union FragU { unsigned u[4]; bf8v v; };

__device__ __forceinline__ void gl_lds16(const void* g, void* l) {
    __builtin_amdgcn_global_load_lds(
        (const __attribute__((address_space(1))) unsigned int*)g,
        (__attribute__((address_space(3))) unsigned int*)l, 16, 0, 0);
}

// Pre-tile classical_weights (fp32 [K][N]) into bf16 hi/lo in the EXACT LDS
// image order: Wt[nblk][stage][granule g], g = kpart*128 + nrow, granule =
// 8 shorts (n = nblk*128+nrow, k = stage*32 + kpart*8 + j). This makes the
// GEMM's B staging perfectly coalesced global_load_lds.
__global__ void split_w_kernel(const float* __restrict__ W,
                               unsigned short* __restrict__ Whi,
                               unsigned short* __restrict__ Wlo) {
    __shared__ float tile[32][132];  // pad 128->132: conflict-free column reads
    const int s = blockIdx.x;        // k-stage 0..127
    const int nblk = blockIdx.y;     // 0..1
    const int t = threadIdx.x;
    #pragma unroll
    for (int i = 0; i < 4; ++i) {
        int flat = i * 1024 + t * 4;
        int k = flat >> 7;           // 0..31
        int n = flat & 127;
        *(float4*)&tile[k][n] =
            *(const float4*)&W[(size_t)(s * 32 + k) * N_DIM + nblk * 128 + n];
    }
    __syncthreads();
    #pragma unroll
    for (int i = 0; i < 2; ++i) {
        int g = i * 256 + t;
        int kpart = g >> 7;          // 0..3
        int nrow = g & 127;
        unsigned short h8[8], l8[8];
        #pragma unroll
        for (int j = 0; j < 8; ++j) {
            float f = tile[kpart * 8 + j][nrow];
            unsigned u = __float_as_uint(f);
            unsigned hh = u + 0x7fffu + ((u >> 16) & 1u);     // RNE bf16
            float r = f - __uint_as_float(hh & 0xffff0000u);  // residual
            h8[j] = (unsigned short)(hh >> 16);
            l8[j] = (unsigned short)(__float_as_uint(r) >> 16);
        }
        size_t o = ((size_t)(nblk * NSTAGES + s) * 512 + g) * 8;
        *(us8*)&Whi[o] = *(us8*)&h8[0];
        *(us8*)&Wlo[o] = *(us8*)&l8[0];
    }
}

// beta[j] = bias[j] + (1/4096) * prod_{d,k} cos^2(uw[d, j, k])
// (state starts uniform along axis1; _rotate maps a uniform row to cos(a)*row)
__global__ void beta_kernel(const float* __restrict__ uw,
                            const float* __restrict__ bias,
                            float* __restrict__ beta) {
    int j = threadIdx.x;
    float p = 1.0f / 4096.0f;
    #pragma unroll
    for (int d = 0; d < 9; ++d) {
        const float* a = uw + (size_t)d * (K_DIM * N_DIM) + (size_t)j * N_DIM;
        #pragma unroll
        for (int k = 0; k < 3; ++k) {
            float c = cosf(a[k]);
            p *= c * c;
        }
    }
    beta[j] = bias[j] + p;
}

__device__ __forceinline__ void cvt8(float4 f0, float4 f1, FragU& hi, FragU& lo) {
    float f[8] = {f0.x, f0.y, f0.z, f0.w, f1.x, f1.y, f1.z, f1.w};
    #pragma unroll
    for (int i = 0; i < 4; ++i) {
        float x0 = f[2 * i], x1 = f[2 * i + 1];
        unsigned u0 = __float_as_uint(x0), u1 = __float_as_uint(x1);
        unsigned h0 = u0 + 0x7fffu + ((u0 >> 16) & 1u);
        unsigned h1 = u1 + 0x7fffu + ((u1 >> 16) & 1u);
        hi.u[i] = (h0 >> 16) | (h1 & 0xffff0000u);
        float r0 = x0 - __uint_as_float(h0 & 0xffff0000u);
        float r1 = x1 - __uint_as_float(h1 & 0xffff0000u);
        lo.u[i] = (__float_as_uint(r0) >> 16) | (__float_as_uint(r1) & 0xffff0000u);
    }
}

__device__ __forceinline__ f4v mfma_bf16(bf8v a, bf8v b, f4v c) {
    return __builtin_amdgcn_mfma_f32_16x16x32_bf16(a, b, c, 0, 0, 0);
}

// Stage one BK=32 tile (A fp32 swizzled image + B hi/lo pre-tiled) into buf.
__device__ __forceinline__ void stage_tile(const float* gA0, const float* gA1,
                                           const unsigned short* gBh,
                                           const unsigned short* gBl,
                                           char* buf, int t, int s) {
    gl_lds16(gA0 + (size_t)s * BK, buf + t * 16);
    gl_lds16(gA1 + (size_t)s * BK, buf + (t + 256) * 16);
    const unsigned short* bh = gBh + (size_t)s * 4096;
    const unsigned short* bl = gBl + (size_t)s * 4096;
    gl_lds16(bh,        buf + 8192  + t * 16);
    gl_lds16(bh + 2048, buf + 8192  + (t + 256) * 16);
    gl_lds16(bl,        buf + 16384 + t * 16);
    gl_lds16(bl + 2048, buf + 16384 + (t + 256) * 16);
}

// out[m,n] = tanh(sum_k x[m,k]*W[k,n] + beta[n]); 3-term bf16 split GEMM.
// BM=64 BN=128 BK=32, 256 thr = 4 waves (wave-tile 32x64), 16x16x32 MFMA.
// ALL staging via coalesced global_load_lds (A: XOR-swizzled fp32 image;
// B: pre-tiled bf16 hi/lo). Double-buffered, one barrier per stage.
__global__ __launch_bounds__(256, 2)
void gemm_tanh_kernel(const float* __restrict__ X,
                      const unsigned short* __restrict__ Whi,
                      const unsigned short* __restrict__ Wlo,
                      const float* __restrict__ beta,
                      float* __restrict__ out) {
    __shared__ __align__(16) char lds[2 * BUF_BYTES];  // 48 KB

    const int t = threadIdx.x;
    const int nblk = blockIdx.x;   // 0..1 (n fastest: m-pair shares x in L2/L3)
    const int n0 = nblk * 128;
    const int m0 = blockIdx.y * 64;

    const int lane = t & 63;
    const int wave = t >> 6;
    const int wm = wave & 1;
    const int wn = wave >> 1;
    const int r16 = lane & 15;
    const int quad = lane >> 4;

    // A staging: slot -> (mrow = slot>>3, khs = slot&7), global kh = khs ^ (mrow&7)
    const float* gA0;
    const float* gA1;
    {
        int s0 = t, s1 = t + 256;
        int mr0 = s0 >> 3, kh0 = (s0 & 7) ^ (mr0 & 7);
        int mr1 = s1 >> 3, kh1 = (s1 & 7) ^ (mr1 & 7);
        gA0 = X + (size_t)(m0 + mr0) * K_DIM + kh0 * 4;
        gA1 = X + (size_t)(m0 + mr1) * K_DIM + kh1 * 4;
    }
    // B staging: thread t owns granules t and t+256 of the stage's 512
    const unsigned short* gBh = Whi + (size_t)nblk * NSTAGES * 4096 + t * 8;
    const unsigned short* gBl = Wlo + (size_t)nblk * NSTAGES * 4096 + t * 8;

    f4v acc[2][4];
    #pragma unroll
    for (int mt = 0; mt < 2; ++mt)
        #pragma unroll
        for (int nt = 0; nt < 4; ++nt)
            acc[mt][nt] = (f4v)(0.0f);

    stage_tile(gA0, gA1, gBh, gBl, lds, t, 0);
    __syncthreads();

    for (int s = 0; s < NSTAGES; ++s) {
        char* bufc = lds + (s & 1) * BUF_BYTES;
        if (s + 1 < NSTAGES)
            stage_tile(gA0, gA1, gBh, gBl, lds + ((s + 1) & 1) * BUF_BYTES, t, s + 1);

        // ---- A fragments: swizzled fp32 from LDS, cvt to bf16 hi/lo ----
        FragU ah[2], al[2];
        #pragma unroll
        for (int mt = 0; mt < 2; ++mt) {
            int mrow = wm * 32 + mt * 16 + r16;
            int khs0 = (quad * 2)     ^ (mrow & 7);
            int khs1 = (quad * 2 + 1) ^ (mrow & 7);
            float4 f0 = *(const float4*)(bufc + (mrow * 8 + khs0) * 16);
            float4 f1 = *(const float4*)(bufc + (mrow * 8 + khs1) * 16);
            cvt8(f0, f1, ah[mt], al[mt]);
        }
        // ---- B fragments ----
        FragU bh[4], bl[4];
        #pragma unroll
        for (int nt = 0; nt < 4; ++nt) {
            int nrow = wn * 64 + nt * 16 + r16;
            bh[nt].v = *(const bf8v*)(bufc + 8192  + (quad * 128 + nrow) * 16);
            bl[nt].v = *(const bf8v*)(bufc + 16384 + (quad * 128 + nrow) * 16);
        }
        // ---- 24 MFMA: 2m x 4n x 3 split-terms ----
        #pragma unroll
        for (int nt = 0; nt < 4; ++nt) {
            acc[0][nt] = mfma_bf16(ah[0].v, bh[nt].v, acc[0][nt]);
            acc[0][nt] = mfma_bf16(al[0].v, bh[nt].v, acc[0][nt]);
            acc[0][nt] = mfma_bf16(ah[0].v, bl[nt].v, acc[0][nt]);
            acc[1][nt] = mfma_bf16(ah[1].v, bh[nt].v, acc[1][nt]);
            acc[1][nt] = mfma_bf16(al[1].v, bh[nt].v, acc[1][nt]);
            acc[1][nt] = mfma_bf16(ah[1].v, bl[nt].v, acc[1][nt]);
        }
        __syncthreads();  // drains next-stage staging; frees bufc for s+2
    }

    // ---- epilogue: + beta, tanh, store ----
    const int nbase = n0 + wn * 64;
    float bet[4];
    #pragma unroll
    for (int nt = 0; nt < 4; ++nt) bet[nt] = beta[nbase + nt * 16 + r16];

    const int mbase = m0 + wm * 32;
    #pragma unroll
    for (int mt = 0; mt < 2; ++mt) {
        #pragma unroll
        for (int nt = 0; nt < 4; ++nt) {
            const int col = nbase + nt * 16 + r16;
            #pragma unroll
            for (int r = 0; r < 4; ++r) {
                const int row = mbase + mt * 16 + quad * 4 + r;
                out[(size_t)row * N_DIM + col] = tanhf(acc[mt][nt][r] + bet[nt]);
            }
        }
    }
}

extern "C" void kernel_launch(void* const* d_in, const int* in_sizes, int n_in,
                              void* d_out, int out_size, void* d_ws, size_t ws_size,
                              hipStream_t stream) {
    const float* x    = (const float*)d_in[0];
    const float* uw   = (const float*)d_in[1];
    const float* W    = (const float*)d_in[2];
    const float* bias = (const float*)d_in[3];
    float* out = (float*)d_out;

    // workspace: Whi tiled (2 MB) | Wlo tiled (2 MB) | beta (1 KB)
    char* ws = (char*)d_ws;
    unsigned short* whi = (unsigned short*)(ws);
    unsigned short* wlo = (unsigned short*)(ws + (size_t)2 * 1024 * 1024);
    float* beta = (float*)(ws + (size_t)4 * 1024 * 1024);

    split_w_kernel<<<dim3(NSTAGES, N_DIM / 128), 256, 0, stream>>>(W, whi, wlo);
    beta_kernel<<<1, 256, 0, stream>>>(uw, bias, beta);

    dim3 grid(N_DIM / 128, M_DIM / 64);
    gemm_tanh_kernel<<<grid, 256, 0, stream>>>(x, whi, wlo, beta, out);
}

// Round 4
// 496.324 us; speedup vs baseline: 1.2620x; 1.0074x over previous
//
#include <hip/hip_runtime.h>
#include <math.h>

#define K_DIM 4096
#define N_DIM 256
#define M_DIM 16384
#define BK 32
#define NSTAGES (K_DIM / BK)   // 128
#define BUF_BYTES 24576        // A 8K | Bh 8K | Bl 8K

typedef short bf8v __attribute__((ext_vector_type(8)));
typedef float f4v __attribute__((ext_vector_type(4)));
typedef unsigned short us8 __attribute__((ext_vector_type(8)));

union FragU { unsigned u[4]; bf8v v; };

__device__ __forceinline__ void gl_lds16(const void* g, void* l) {
    __builtin_amdgcn_global_load_lds(
        (const __attribute__((address_space(1))) unsigned int*)g,
        (__attribute__((address_space(3))) unsigned int*)l, 16, 0, 0);
}

// Pre-tile classical_weights (fp32 [K][N]) into bf16 hi/lo in the EXACT LDS
// image order: Wt[nblk][stage][granule g], g = kpart*128 + nrow, granule =
// 8 shorts (n = nblk*128+nrow, k = stage*32 + kpart*8 + j). This makes the
// GEMM's B staging perfectly coalesced global_load_lds.
__global__ void split_w_kernel(const float* __restrict__ W,
                               unsigned short* __restrict__ Whi,
                               unsigned short* __restrict__ Wlo) {
    __shared__ float tile[32][132];  // pad 128->132: conflict-free column reads
    const int s = blockIdx.x;        // k-stage 0..127
    const int nblk = blockIdx.y;     // 0..1
    const int t = threadIdx.x;
    #pragma unroll
    for (int i = 0; i < 4; ++i) {
        int flat = i * 1024 + t * 4;
        int k = flat >> 7;           // 0..31
        int n = flat & 127;
        *(float4*)&tile[k][n] =
            *(const float4*)&W[(size_t)(s * 32 + k) * N_DIM + nblk * 128 + n];
    }
    __syncthreads();
    #pragma unroll
    for (int i = 0; i < 2; ++i) {
        int g = i * 256 + t;
        int kpart = g >> 7;          // 0..3
        int nrow = g & 127;
        unsigned short h8[8], l8[8];
        #pragma unroll
        for (int j = 0; j < 8; ++j) {
            float f = tile[kpart * 8 + j][nrow];
            unsigned u = __float_as_uint(f);
            unsigned hh = u + 0x7fffu + ((u >> 16) & 1u);     // RNE bf16
            float r = f - __uint_as_float(hh & 0xffff0000u);  // residual
            h8[j] = (unsigned short)(hh >> 16);
            l8[j] = (unsigned short)(__float_as_uint(r) >> 16);
        }
        size_t o = ((size_t)(nblk * NSTAGES + s) * 512 + g) * 8;
        *(us8*)&Whi[o] = *(us8*)&h8[0];
        *(us8*)&Wlo[o] = *(us8*)&l8[0];
    }
}

// beta[j] = bias[j] + (1/4096) * prod_{d,k} cos^2(uw[d, j, k])
// (state starts uniform along axis1; _rotate maps a uniform row to cos(a)*row)
__global__ void beta_kernel(const float* __restrict__ uw,
                            const float* __restrict__ bias,
                            float* __restrict__ beta) {
    int j = threadIdx.x;
    float p = 1.0f / 4096.0f;
    #pragma unroll
    for (int d = 0; d < 9; ++d) {
        const float* a = uw + (size_t)d * (K_DIM * N_DIM) + (size_t)j * N_DIM;
        #pragma unroll
        for (int k = 0; k < 3; ++k) {
            float c = cosf(a[k]);
            p *= c * c;
        }
    }
    beta[j] = bias[j] + p;
}

__device__ __forceinline__ void cvt8(float4 f0, float4 f1, FragU& hi, FragU& lo) {
    float f[8] = {f0.x, f0.y, f0.z, f0.w, f1.x, f1.y, f1.z, f1.w};
    #pragma unroll
    for (int i = 0; i < 4; ++i) {
        float x0 = f[2 * i], x1 = f[2 * i + 1];
        unsigned u0 = __float_as_uint(x0), u1 = __float_as_uint(x1);
        unsigned h0 = u0 + 0x7fffu + ((u0 >> 16) & 1u);
        unsigned h1 = u1 + 0x7fffu + ((u1 >> 16) & 1u);
        hi.u[i] = (h0 >> 16) | (h1 & 0xffff0000u);
        float r0 = x0 - __uint_as_float(h0 & 0xffff0000u);
        float r1 = x1 - __uint_as_float(h1 & 0xffff0000u);
        lo.u[i] = (__float_as_uint(r0) >> 16) | (__float_as_uint(r1) & 0xffff0000u);
    }
}

__device__ __forceinline__ f4v mfma_bf16(bf8v a, bf8v b, f4v c) {
    return __builtin_amdgcn_mfma_f32_16x16x32_bf16(a, b, c, 0, 0, 0);
}

// Stage one BK=32 tile (A fp32 swizzled image + B hi/lo pre-tiled) into buf.
// 6 global_load_lds per thread -> each wave adds 6 to its vmcnt.
__device__ __forceinline__ void stage_tile(const float* gA0, const float* gA1,
                                           const unsigned short* gBh,
                                           const unsigned short* gBl,
                                           char* buf, int t, int s) {
    gl_lds16(gA0 + (size_t)s * BK, buf + t * 16);
    gl_lds16(gA1 + (size_t)s * BK, buf + (t + 256) * 16);
    const unsigned short* bh = gBh + (size_t)s * 4096;
    const unsigned short* bl = gBl + (size_t)s * 4096;
    gl_lds16(bh,        buf + 8192  + t * 16);
    gl_lds16(bh + 2048, buf + 8192  + (t + 256) * 16);
    gl_lds16(bl,        buf + 16384 + t * 16);
    gl_lds16(bl + 2048, buf + 16384 + (t + 256) * 16);
}

// out[m,n] = tanh(sum_k x[m,k]*W[k,n] + beta[n]); 3-term bf16 split GEMM.
// BM=64 BN=128 BK=32, 256 thr = 4 waves (wave-tile 32x64), 16x16x32 MFMA.
// Triple-buffered LDS, prefetch depth 2, RAW s_barrier + manual
// s_waitcnt vmcnt(6): each wave waits only its own stage-s loads (stage s+1
// stays in flight across the barrier), then issues stage s+2 into the
// buffer last read at s-1. No __syncthreads -> no vmcnt(0) drain per stage.
__global__ __launch_bounds__(256, 2)
void gemm_tanh_kernel(const float* __restrict__ X,
                      const unsigned short* __restrict__ Whi,
                      const unsigned short* __restrict__ Wlo,
                      const float* __restrict__ beta,
                      float* __restrict__ out) {
    __shared__ __align__(16) char lds[3 * BUF_BYTES];  // 72 KB -> 2 blocks/CU

    const int t = threadIdx.x;
    const int nblk = blockIdx.x;   // 0..1 (n fastest: m-pair shares x in L2/L3)
    const int n0 = nblk * 128;
    const int m0 = blockIdx.y * 64;

    const int lane = t & 63;
    const int wave = t >> 6;
    const int wm = wave & 1;
    const int wn = wave >> 1;
    const int r16 = lane & 15;
    const int quad = lane >> 4;

    // A staging: slot -> (mrow = slot>>3, khs = slot&7), global kh = khs ^ (mrow&7)
    const float* gA0;
    const float* gA1;
    {
        int s0 = t, s1 = t + 256;
        int mr0 = s0 >> 3, kh0 = (s0 & 7) ^ (mr0 & 7);
        int mr1 = s1 >> 3, kh1 = (s1 & 7) ^ (mr1 & 7);
        gA0 = X + (size_t)(m0 + mr0) * K_DIM + kh0 * 4;
        gA1 = X + (size_t)(m0 + mr1) * K_DIM + kh1 * 4;
    }
    // B staging: thread t owns granules t and t+256 of the stage's 512
    const unsigned short* gBh = Whi + (size_t)nblk * NSTAGES * 4096 + t * 8;
    const unsigned short* gBl = Wlo + (size_t)nblk * NSTAGES * 4096 + t * 8;

    f4v acc[2][4];
    #pragma unroll
    for (int mt = 0; mt < 2; ++mt)
        #pragma unroll
        for (int nt = 0; nt < 4; ++nt)
            acc[mt][nt] = (f4v)(0.0f);

    char* b0 = lds;                  // compute buffer this iter
    char* b1 = lds + BUF_BYTES;      // next iter's buffer (in flight)
    char* b2 = lds + 2 * BUF_BYTES;  // free: staged this iter for s+2

    stage_tile(gA0, gA1, gBh, gBl, b0, t, 0);
    stage_tile(gA0, gA1, gBh, gBl, b1, t, 1);

    for (int s = 0; s < NSTAGES; ++s) {
        if (s < NSTAGES - 2) {
            // Wait own stage-s 6 loads (12 outstanding -> 6), sync, then
            // prefetch stage s+2 into b2 (last read at iter s-1; every wave
            // finished consuming it before its barrier).
            asm volatile("s_waitcnt vmcnt(6)\n\ts_barrier" ::: "memory");
            stage_tile(gA0, gA1, gBh, gBl, b2, t, s + 2);
        } else {
            asm volatile("s_waitcnt vmcnt(0)\n\ts_barrier" ::: "memory");
        }

        // ---- A fragments: swizzled fp32 from LDS, cvt to bf16 hi/lo ----
        FragU ah[2], al[2];
        #pragma unroll
        for (int mt = 0; mt < 2; ++mt) {
            int mrow = wm * 32 + mt * 16 + r16;
            int khs0 = (quad * 2)     ^ (mrow & 7);
            int khs1 = (quad * 2 + 1) ^ (mrow & 7);
            float4 f0 = *(const float4*)(b0 + (mrow * 8 + khs0) * 16);
            float4 f1 = *(const float4*)(b0 + (mrow * 8 + khs1) * 16);
            cvt8(f0, f1, ah[mt], al[mt]);
        }
        // ---- B fragments ----
        FragU bh[4], bl[4];
        #pragma unroll
        for (int nt = 0; nt < 4; ++nt) {
            int nrow = wn * 64 + nt * 16 + r16;
            bh[nt].v = *(const bf8v*)(b0 + 8192  + (quad * 128 + nrow) * 16);
            bl[nt].v = *(const bf8v*)(b0 + 16384 + (quad * 128 + nrow) * 16);
        }
        // ---- 24 MFMA: 2m x 4n x 3 split-terms ----
        #pragma unroll
        for (int nt = 0; nt < 4; ++nt) {
            acc[0][nt] = mfma_bf16(ah[0].v, bh[nt].v, acc[0][nt]);
            acc[0][nt] = mfma_bf16(al[0].v, bh[nt].v, acc[0][nt]);
            acc[0][nt] = mfma_bf16(ah[0].v, bl[nt].v, acc[0][nt]);
            acc[1][nt] = mfma_bf16(ah[1].v, bh[nt].v, acc[1][nt]);
            acc[1][nt] = mfma_bf16(al[1].v, bh[nt].v, acc[1][nt]);
            acc[1][nt] = mfma_bf16(ah[1].v, bl[nt].v, acc[1][nt]);
        }

        // rotate buffers
        char* tmp = b0; b0 = b1; b1 = b2; b2 = tmp;
    }

    // ---- epilogue: + beta, tanh, store ----
    const int nbase = n0 + wn * 64;
    float bet[4];
    #pragma unroll
    for (int nt = 0; nt < 4; ++nt) bet[nt] = beta[nbase + nt * 16 + r16];

    const int mbase = m0 + wm * 32;
    #pragma unroll
    for (int mt = 0; mt < 2; ++mt) {
        #pragma unroll
        for (int nt = 0; nt < 4; ++nt) {
            const int col = nbase + nt * 16 + r16;
            #pragma unroll
            for (int r = 0; r < 4; ++r) {
                const int row = mbase + mt * 16 + quad * 4 + r;
                out[(size_t)row * N_DIM + col] = tanhf(acc[mt][nt][r] + bet[nt]);
            }
        }
    }
}

extern "C" void kernel_launch(void* const* d_in, const int* in_sizes, int n_in,
                              void* d_out, int out_size, void* d_ws, size_t ws_size,
                              hipStream_t stream) {
    const float* x    = (const float*)d_in[0];
    const float* uw   = (const float*)d_in[1];
    const float* W    = (const float*)d_in[2];
    const float* bias = (const float*)d_in[3];
    float* out = (float*)d_out;

    // workspace: Whi tiled (2 MB) | Wlo tiled (2 MB) | beta (1 KB)
    char* ws = (char*)d_ws;
    unsigned short* whi = (unsigned short*)(ws);
    unsigned short* wlo = (unsigned short*)(ws + (size_t)2 * 1024 * 1024);
    float* beta = (float*)(ws + (size_t)4 * 1024 * 1024);

    split_w_kernel<<<dim3(NSTAGES, N_DIM / 128), 256, 0, stream>>>(W, whi, wlo);
    beta_kernel<<<1, 256, 0, stream>>>(uw, bias, beta);

    dim3 grid(N_DIM / 128, M_DIM / 64);
    gemm_tanh_kernel<<<grid, 256, 0, stream>>>(x, whi, wlo, beta, out);
}